// Round 14
// baseline (293.846 us; speedup 1.0000x reference)
//
#include <hip/hip_runtime.h>
#include <math.h>

// Problem constants
#define TB 2
#define TT 31
#define TH 160
#define TW 160
#define THW (TH*TW)            // 25600
#define NPER (TB*TT*THW)       // 1,587,200
#define HCN 16
#define LSK 40                 // k1 LDS row stride

// Workspace layout (bytes). gates bf16: z-half [0,50.79MB), f-half [50.79,101.58MB).
// After k3, z-half is overwritten in-place with h (bf16). c2/c3 fp32 alias the
// (dead) f-half. Stats at the end. Total ~101.6MB.
#define GF_OFF_US  25395200L    // ushort offset of f-gates (2*16*31*25600)
#define C2_BYTE    50790400L    // byte offset of c2 (aliases f-gates, dead by then)
#define STATS_BYTE 101580800L

__device__ __forceinline__ float sigmoidf_(float x) {
    return __builtin_amdgcn_rcpf(1.f + __expf(-x));
}
__device__ __forceinline__ float tanhf_(float x) {
    return 2.f * __builtin_amdgcn_rcpf(1.f + __expf(-2.f * x)) - 1.f;
}
__device__ __forceinline__ unsigned short f2bf(float v) {
    unsigned int b = __float_as_uint(v);
    unsigned int r = (b + 0x7FFFu + ((b >> 16) & 1u)) >> 16;   // RNE
    return (unsigned short)r;
}
__device__ __forceinline__ float b2f(unsigned short u) {
    return __uint_as_float(((unsigned int)u) << 16);
}

// ---------- kernel 1 (R9-proven): conv1 via LDS staging, no mid-loop barriers,
//            per-channel sum/sumsq + bf16 gate store ----------
// grid: (8 = chalf*4 + tchunk, 100 tiles 32x8, 2 b), block 256
__global__ __launch_bounds__(256)
void k1_gates_stats(const float* __restrict__ in, const float* __restrict__ wg,
                    unsigned short* __restrict__ gout, float* __restrict__ stats) {
    __shared__ float pl[10*10*LSK];          // 10 t-planes, 10 rows x 40 (34 used)
    __shared__ float redS[4][16], redQ[4][16];

    int bx = blockIdx.x;
    int tc = bx & 3, chalf = bx >> 2;
    int tile = blockIdx.y, b = blockIdx.z;
    int ty0 = (tile / 5) * 8, tx0 = (tile % 5) * 32;
    int tid = threadIdx.x;
    int lyk = tid >> 5, lxk = tid & 31;
    int t0 = tc * 8;

    // stage 10 halo planes (t0-1 .. t0+8), 10x34 each, zero-padded
    for (int i = tid; i < 3400; i += 256) {
        int j = i / 340, pos = i - j*340;
        int py = pos / 34, px = pos - py*34;
        int t = t0 - 1 + j;
        int gy = ty0 - 1 + py, gx = tx0 - 1 + px;
        float v = 0.f;
        if (t >= 0 && t < TT && gy >= 0 && gy < TH && gx >= 0 && gx < TW)
            v = in[((long)(b*TT + t))*THW + gy*TW + gx];
        pl[j*(10*LSK) + py*LSK + px] = v;
    }
    __syncthreads();

    int c0 = chalf * 16;
    long gbase = chalf ? GF_OFF_US : 0L;
    int y = ty0 + lyk, x = tx0 + lxk;
    int hw = y*TW + x;

    float s[16], q[16];
    #pragma unroll
    for (int c = 0; c < 16; ++c) { s[c] = 0.f; q[c] = 0.f; }

    for (int j = 1; j <= 8; ++j) {
        int t = t0 - 1 + j;
        if (t >= TT) break;                  // uniform
        float tap[27];
        #pragma unroll
        for (int kt = 0; kt < 3; ++kt)
            #pragma unroll
            for (int ky = 0; ky < 3; ++ky)
                #pragma unroll
                for (int kx = 0; kx < 3; ++kx)
                    tap[kt*9 + ky*3 + kx] =
                        pl[(j-1+kt)*(10*LSK) + (lyk+ky)*LSK + (lxk+kx)];
        #pragma unroll
        for (int c = 0; c < 16; ++c) {
            const float* w = wg + (c0 + c)*27;
            float v = 0.f;
            #pragma unroll
            for (int i = 0; i < 27; ++i) v = fmaf(w[i], tap[i], v);
            s[c] += v; q[c] += v*v;
            gout[gbase + ((long)((b*HCN + c)*TT + t))*THW + hw] = f2bf(v);
        }
    }

    // block reduce 16 channels x (sum, sumsq)
    int lane = tid & 63, wid = tid >> 6;
    #pragma unroll
    for (int c = 0; c < 16; ++c) {
        float ss = s[c], qq = q[c];
        #pragma unroll
        for (int off = 32; off > 0; off >>= 1) {
            ss += __shfl_down(ss, off, 64);
            qq += __shfl_down(qq, off, 64);
        }
        if (lane == 0) { redS[wid][c] = ss; redQ[wid][c] = qq; }
    }
    __syncthreads();
    if (tid < 16) {
        int ch = c0 + tid;
        float ss = redS[0][tid] + redS[1][tid] + redS[2][tid] + redS[3][tid];
        float qq = redQ[0][tid] + redQ[1][tid] + redQ[2][tid] + redQ[3][tid];
        atomicAdd(&stats[ch], ss);
        atomicAdd(&stats[32 + ch], qq);
    }
}

// ---------- kernel 2: finalize gate BN params ----------
__global__ void k2_fin1(const float* __restrict__ stats, const float* __restrict__ gamma,
                        const float* __restrict__ beta, float* __restrict__ ab) {
    int c = threadIdx.x;
    if (c < 32) {
        float n = (float)NPER;
        float mean = stats[c] / n;
        float var  = stats[32 + c] / n - mean*mean;
        float a = gamma[c] * rsqrtf(var + 1e-5f);
        ab[c]      = a;
        ab[32 + c] = beta[c] - mean * a;
    }
}

// ---------- kernel 3: pointwise BN + act + scan (bf16 in, bf16 h in-place) ----------
// grid: (50, 16 ch, 2 b), block 256; each thread: 2 consecutive hw elems, scans t.
// ushort2 granularity doubles wave count (6400 waves) for latency hiding.
__global__ __launch_bounds__(256)
void k3_scan(unsigned short* __restrict__ g, const float* __restrict__ ab,
             const int* __restrict__ rev_p) {
    int c = blockIdx.y, b = blockIdx.z;
    int p2i = blockIdx.x * blockDim.x + threadIdx.x;   // ushort2 index in plane
    float az = ab[c],      bz = ab[32 + c];
    float af = ab[16 + c], bf = ab[48 + c];
    int rev = rev_p[0];

    ushort2* g2 = (ushort2*)g;
    long zb = ((long)((b*HCN + c)*TT)) * (THW/2) + p2i;
    long fb = zb + GF_OFF_US/2;

    float h0 = 0.f, h1 = 0.f;

#define K3_STEP(t)                                                        \
    {                                                                     \
        long o = (long)(t) * (THW/2);                                     \
        ushort2 zu = g2[zb + o];                                          \
        ushort2 fu = g2[fb + o];                                          \
        float z0 = tanhf_(fmaf(az, b2f(zu.x), bz));                       \
        float z1 = tanhf_(fmaf(az, b2f(zu.y), bz));                       \
        float f0 = sigmoidf_(fmaf(af, b2f(fu.x), bf));                    \
        float f1 = sigmoidf_(fmaf(af, b2f(fu.y), bf));                    \
        h0 = f0*h0 + (1.f - f0)*z0;                                       \
        h1 = f1*h1 + (1.f - f1)*z1;                                       \
        ushort2 hu;                                                       \
        hu.x = f2bf(h0); hu.y = f2bf(h1);                                 \
        g2[zb + o] = hu;                                                  \
    }

    if (!rev) {
        for (int t = 0; t < TT; ++t) K3_STEP(t)
    } else {
        for (int t = TT - 1; t >= 0; --t) K3_STEP(t)
    }
#undef K3_STEP
}

// ---------- kernel 4: conv2+conv3 over bf16 h — NO LDS, NO BARRIERS.
// Each thread: 2 x-outputs; per plane, 3 aligned uint (bf16-pair) loads per row
// straight from global (L1/L2 absorb neighbor overlap). Edge zero-padding folded
// into precomputed per-thread AND-masks. K4TCH=2 -> 1600 blocks (78% occ cap).
// grid: (50 tiles 32x16, 16 t-chunks of 2, 2 b), block 256
#define K4TCH 2
__global__ __launch_bounds__(256)
void k4_conv23(const unsigned short* __restrict__ hb, const float* __restrict__ wsc,
               const float* __restrict__ wsh, float* __restrict__ c2,
               float* __restrict__ c3, float* __restrict__ stats2) {
    __shared__ float red[4][4];

    int b  = blockIdx.z;
    int t0 = blockIdx.y * K4TCH;
    int t1 = min(t0 + K4TCH - 1, TT - 1);
    int tile = blockIdx.x;
    int ty0 = (tile / 5) * 16, tx0 = (tile % 5) * 32;
    int tid = threadIdx.x;
    int k   = tid & 15;            // x-pair index
    int ly  = tid >> 4;            // row 0..15
    int y = ty0 + ly, x0 = tx0 + 2*k;

    int ts = max(t0 - 1, 0), te = min(t1 + 1, TT - 1);
    int nplanes = (te - ts + 1) * 8;

    // per-thread constants: uint element offsets within a plane, per-row masks
    int e0 = max(x0 - 2, 0) >> 1;
    int e1 = x0 >> 1;
    int e2 = min(x0 + 2, TW - 2) >> 1;
    unsigned int mL = (x0 == 0)      ? 0u : 0xffff0000u;
    unsigned int mR = (x0 == TW - 2) ? 0u : 0x0000ffffu;
    int rowb[3];
    unsigned int mHi0[3], mRow[3], mLo2[3];
    #pragma unroll
    for (int ky = 0; ky < 3; ++ky) {
        int gy = y - 1 + ky;
        bool ok = (gy >= 0 && gy < TH);
        int gyc = min(max(gy, 0), TH - 1);
        rowb[ky] = gyc * (TW/2);
        unsigned int rm = ok ? 0xffffffffu : 0u;
        mHi0[ky] = rm & mL;
        mRow[ky] = rm;
        mLo2[ky] = rm & mR;
    }

    float aP2x=0.f,aP2y=0.f,aC2x=0.f,aC2y=0.f,aN2x=0.f,aN2y=0.f;
    float aP3x=0.f,aP3y=0.f,aC3x=0.f,aC3y=0.f,aN3x=0.f,aN3y=0.f;
    float s2l = 0.f, q2l = 0.f, s3l = 0.f, q3l = 0.f;

    #pragma unroll 1
    for (int p = 0; p < nplanes; ++p) {
        int c = p & 7, t_in = ts + (p >> 3);
        const unsigned int* p2 = (const unsigned int*)(hb + ((long)((b*HCN + c)*TT + t_in))*THW);
        const unsigned int* p3 = (const unsigned int*)(hb + ((long)((b*HCN + 8 + c)*TT + t_in))*THW);
        const float* w2 = wsc + c*27;
        const float* w3 = wsh + c*27;

        #pragma unroll
        for (int ky = 0; ky < 3; ++ky) {
            int rb = rowb[ky];
            // conv2
            {
                unsigned int u0 = p2[rb + e0];
                unsigned int u1 = p2[rb + e1];
                unsigned int u2 = p2[rb + e2];
                float v1 = __uint_as_float(u0 & mHi0[ky]);         // x0-1
                unsigned int tm = u1 & mRow[ky];
                float v2 = __uint_as_float(tm << 16);              // x0
                float v3 = __uint_as_float(tm & 0xffff0000u);      // x0+1
                float v4 = __uint_as_float((u2 & mLo2[ky]) << 16); // x0+2
                float wN0 = w2[ky*3+0],   wN1 = w2[ky*3+1],   wN2 = w2[ky*3+2];
                float wC0 = w2[9+ky*3+0], wC1 = w2[9+ky*3+1], wC2 = w2[9+ky*3+2];
                float wP0 = w2[18+ky*3+0],wP1 = w2[18+ky*3+1],wP2 = w2[18+ky*3+2];
                aN2x = fmaf(wN0,v1,aN2x); aN2x = fmaf(wN1,v2,aN2x); aN2x = fmaf(wN2,v3,aN2x);
                aN2y = fmaf(wN0,v2,aN2y); aN2y = fmaf(wN1,v3,aN2y); aN2y = fmaf(wN2,v4,aN2y);
                aC2x = fmaf(wC0,v1,aC2x); aC2x = fmaf(wC1,v2,aC2x); aC2x = fmaf(wC2,v3,aC2x);
                aC2y = fmaf(wC0,v2,aC2y); aC2y = fmaf(wC1,v3,aC2y); aC2y = fmaf(wC2,v4,aC2y);
                aP2x = fmaf(wP0,v1,aP2x); aP2x = fmaf(wP1,v2,aP2x); aP2x = fmaf(wP2,v3,aP2x);
                aP2y = fmaf(wP0,v2,aP2y); aP2y = fmaf(wP1,v3,aP2y); aP2y = fmaf(wP2,v4,aP2y);
            }
            // conv3
            {
                unsigned int u0 = p3[rb + e0];
                unsigned int u1 = p3[rb + e1];
                unsigned int u2 = p3[rb + e2];
                float v1 = __uint_as_float(u0 & mHi0[ky]);
                unsigned int tm = u1 & mRow[ky];
                float v2 = __uint_as_float(tm << 16);
                float v3 = __uint_as_float(tm & 0xffff0000u);
                float v4 = __uint_as_float((u2 & mLo2[ky]) << 16);
                float wN0 = w3[ky*3+0],   wN1 = w3[ky*3+1],   wN2 = w3[ky*3+2];
                float wC0 = w3[9+ky*3+0], wC1 = w3[9+ky*3+1], wC2 = w3[9+ky*3+2];
                float wP0 = w3[18+ky*3+0],wP1 = w3[18+ky*3+1],wP2 = w3[18+ky*3+2];
                aN3x = fmaf(wN0,v1,aN3x); aN3x = fmaf(wN1,v2,aN3x); aN3x = fmaf(wN2,v3,aN3x);
                aN3y = fmaf(wN0,v2,aN3y); aN3y = fmaf(wN1,v3,aN3y); aN3y = fmaf(wN2,v4,aN3y);
                aC3x = fmaf(wC0,v1,aC3x); aC3x = fmaf(wC1,v2,aC3x); aC3x = fmaf(wC2,v3,aC3x);
                aC3y = fmaf(wC0,v2,aC3y); aC3y = fmaf(wC1,v3,aC3y); aC3y = fmaf(wC2,v4,aC3y);
                aP3x = fmaf(wP0,v1,aP3x); aP3x = fmaf(wP1,v2,aP3x); aP3x = fmaf(wP2,v3,aP3x);
                aP3y = fmaf(wP0,v2,aP3y); aP3y = fmaf(wP1,v3,aP3y); aP3y = fmaf(wP2,v4,aP3y);
            }
        }

        if (c == 7) {
            int t_out = t_in - 1;
            if (t_out >= t0 && t_out <= t1) {
                long oidx = ((long)(b*TT + t_out)) * THW + (long)y*TW + x0;
                *(float2*)&c2[oidx] = make_float2(aP2x, aP2y);
                *(float2*)&c3[oidx] = make_float2(aP3x, aP3y);
                s2l += aP2x + aP2y; q2l += aP2x*aP2x + aP2y*aP2y;
                s3l += aP3x + aP3y; q3l += aP3x*aP3x + aP3y*aP3y;
            }
            aP2x=aC2x; aC2x=aN2x; aN2x=0.f;  aP2y=aC2y; aC2y=aN2y; aN2y=0.f;
            aP3x=aC3x; aC3x=aN3x; aN3x=0.f;  aP3y=aC3y; aC3y=aN3y; aN3y=0.f;
        }
    }
    if (t1 == TT - 1) {
        long oidx = ((long)(b*TT + (TT - 1))) * THW + (long)y*TW + x0;
        *(float2*)&c2[oidx] = make_float2(aP2x, aP2y);
        *(float2*)&c3[oidx] = make_float2(aP3x, aP3y);
        s2l += aP2x + aP2y; q2l += aP2x*aP2x + aP2y*aP2y;
        s3l += aP3x + aP3y; q3l += aP3x*aP3x + aP3y*aP3y;
    }

    #pragma unroll
    for (int off = 32; off > 0; off >>= 1) {
        s2l += __shfl_down(s2l, off, 64);
        q2l += __shfl_down(q2l, off, 64);
        s3l += __shfl_down(s3l, off, 64);
        q3l += __shfl_down(q3l, off, 64);
    }
    int lane = tid & 63, wid = tid >> 6;
    if (lane == 0) { red[0][wid] = s2l; red[1][wid] = q2l; red[2][wid] = s3l; red[3][wid] = q3l; }
    __syncthreads();
    if (tid == 0) {
        #pragma unroll
        for (int j = 0; j < 4; ++j)
            atomicAdd(&stats2[j], red[j][0] + red[j][1] + red[j][2] + red[j][3]);
    }
}

// ---------- kernel 5: finalize scale/shift BN params ----------
__global__ void k5_fin2(const float* __restrict__ stats2,
                        const float* __restrict__ gs, const float* __restrict__ bs,
                        const float* __restrict__ gt, const float* __restrict__ bt,
                        float* __restrict__ ab2) {
    if (threadIdx.x == 0) {
        float n = (float)NPER;
        float m2 = stats2[0] / n, v2 = stats2[1] / n - m2*m2;
        float a2 = gs[0] * rsqrtf(v2 + 1e-5f);
        ab2[0] = a2; ab2[1] = bs[0] - m2*a2;
        float m3 = stats2[2] / n, v3 = stats2[3] / n - m3*m3;
        float a3 = gt[0] * rsqrtf(v3 + 1e-5f);
        ab2[2] = a3; ab2[3] = bt[0] - m3*a3;
    }
}

// ---------- kernel 6: epilogue, float4 ----------
__global__ __launch_bounds__(256)
void k6_final(const float4* __restrict__ c2, const float4* __restrict__ c3,
              const float* __restrict__ ab2, float4* __restrict__ out) {
    int i = blockIdx.x * blockDim.x + threadIdx.x;
    if (i < NPER/4) {
        float a2 = ab2[0], b2 = ab2[1], a3 = ab2[2], b3 = ab2[3];
        float4 v2 = c2[i], v3 = c3[i];
        float4 sc, sh;
        sc.x = sigmoidf_(fmaf(a2, v2.x, b2) + 2.f) + 1e-4f;
        sc.y = sigmoidf_(fmaf(a2, v2.y, b2) + 2.f) + 1e-4f;
        sc.z = sigmoidf_(fmaf(a2, v2.z, b2) + 2.f) + 1e-4f;
        sc.w = sigmoidf_(fmaf(a2, v2.w, b2) + 2.f) + 1e-4f;
        sh.x = fmaf(a3, v3.x, b3);
        sh.y = fmaf(a3, v3.y, b3);
        sh.z = fmaf(a3, v3.z, b3);
        sh.w = fmaf(a3, v3.w, b3);
        out[i] = sc;
        out[NPER/4 + i] = sh;
    }
}

// ---------- launch ----------
extern "C" void kernel_launch(void* const* d_in, const int* in_sizes, int n_in,
                              void* d_out, int out_size, void* d_ws, size_t ws_size,
                              hipStream_t stream) {
    const float* in          = (const float*)d_in[0];
    const float* w_gate      = (const float*)d_in[1];
    const float* gamma_gate  = (const float*)d_in[2];
    const float* beta_gate   = (const float*)d_in[3];
    const float* w_scale     = (const float*)d_in[4];
    const float* gamma_scale = (const float*)d_in[5];
    const float* beta_scale  = (const float*)d_in[6];
    const float* w_shift     = (const float*)d_in[7];
    const float* gamma_shift = (const float*)d_in[8];
    const float* beta_shift  = (const float*)d_in[9];
    const int*   rev         = (const int*)d_in[10];

    unsigned short* g   = (unsigned short*)d_ws;                    // gates bf16 (z then f); z-half becomes h
    float* c2  = (float*)((char*)d_ws + C2_BYTE);                   // aliases dead f-gates
    float* c3  = c2 + NPER;
    float* st  = (float*)((char*)d_ws + STATS_BYTE);
    float* s1  = st;            // 64
    float* ab1 = st + 64;       // 64
    float* s2  = st + 128;      // 4
    float* ab2 = st + 132;      // 4
    float* out = (float*)d_out;

    hipMemsetAsync(st, 0, 136 * sizeof(float), stream);

    k1_gates_stats<<<dim3(8, 100, TB), 256, 0, stream>>>(in, w_gate, g, s1);
    k2_fin1<<<1, 32, 0, stream>>>(s1, gamma_gate, beta_gate, ab1);
    k3_scan<<<dim3(50, HCN, TB), 256, 0, stream>>>(g, ab1, rev);
    k4_conv23<<<dim3(50, 16, TB), 256, 0, stream>>>(g, w_scale, w_shift, c2, c3, s2);
    k5_fin2<<<1, 64, 0, stream>>>(s2, gamma_scale, beta_scale, gamma_shift, beta_shift, ab2);
    k6_final<<<(NPER/4 + 255)/256, 256, 0, stream>>>((const float4*)c2, (const float4*)c3, ab2, (float4*)out);
}

// Round 16
// 246.542 us; speedup vs baseline: 1.1919x; 1.1919x over previous
//
#include <hip/hip_runtime.h>
#include <math.h>

// Problem constants
#define TB 2
#define TT 31
#define TH 160
#define TW 160
#define THW (TH*TW)            // 25600
#define NPER (TB*TT*THW)       // 1,587,200
#define HCN 16
#define LSK 40                 // k1 LDS row stride

// Workspace layout (bytes). gates bf16: z-half [0,50.79MB), f-half [50.79,101.58MB).
// After k3, z-half is overwritten in-place with h (bf16). c2/c3 (bf16) alias the
// (dead) f-half. Stats at the end. Total ~101.6MB.
#define GF_OFF_US  25395200L    // ushort offset of f-gates (2*16*31*25600)
#define C2_BYTE    50790400L    // byte offset of c2 bf16 (aliases f-gates, dead by then)
#define STATS_BYTE 101580800L

__device__ __forceinline__ float sigmoidf_(float x) {
    return __builtin_amdgcn_rcpf(1.f + __expf(-x));
}
__device__ __forceinline__ float tanhf_(float x) {
    return 2.f * __builtin_amdgcn_rcpf(1.f + __expf(-2.f * x)) - 1.f;
}
__device__ __forceinline__ unsigned short f2bf(float v) {
    unsigned int b = __float_as_uint(v);
    unsigned int r = (b + 0x7FFFu + ((b >> 16) & 1u)) >> 16;   // RNE
    return (unsigned short)r;
}
__device__ __forceinline__ float b2f(unsigned short u) {
    return __uint_as_float(((unsigned int)u) << 16);
}

// ---------- kernel 1 (R9-proven): conv1 via LDS staging, no mid-loop barriers,
//            per-channel sum/sumsq + bf16 gate store ----------
// grid: (8 = chalf*4 + tchunk, 100 tiles 32x8, 2 b), block 256
__global__ __launch_bounds__(256)
void k1_gates_stats(const float* __restrict__ in, const float* __restrict__ wg,
                    unsigned short* __restrict__ gout, float* __restrict__ stats) {
    __shared__ float pl[10*10*LSK];          // 10 t-planes, 10 rows x 40 (34 used)
    __shared__ float redS[4][16], redQ[4][16];

    int bx = blockIdx.x;
    int tc = bx & 3, chalf = bx >> 2;
    int tile = blockIdx.y, b = blockIdx.z;
    int ty0 = (tile / 5) * 8, tx0 = (tile % 5) * 32;
    int tid = threadIdx.x;
    int lyk = tid >> 5, lxk = tid & 31;
    int t0 = tc * 8;

    // stage 10 halo planes (t0-1 .. t0+8), 10x34 each, zero-padded
    for (int i = tid; i < 3400; i += 256) {
        int j = i / 340, pos = i - j*340;
        int py = pos / 34, px = pos - py*34;
        int t = t0 - 1 + j;
        int gy = ty0 - 1 + py, gx = tx0 - 1 + px;
        float v = 0.f;
        if (t >= 0 && t < TT && gy >= 0 && gy < TH && gx >= 0 && gx < TW)
            v = in[((long)(b*TT + t))*THW + gy*TW + gx];
        pl[j*(10*LSK) + py*LSK + px] = v;
    }
    __syncthreads();

    int c0 = chalf * 16;
    long gbase = chalf ? GF_OFF_US : 0L;
    int y = ty0 + lyk, x = tx0 + lxk;
    int hw = y*TW + x;

    float s[16], q[16];
    #pragma unroll
    for (int c = 0; c < 16; ++c) { s[c] = 0.f; q[c] = 0.f; }

    for (int j = 1; j <= 8; ++j) {
        int t = t0 - 1 + j;
        if (t >= TT) break;                  // uniform
        float tap[27];
        #pragma unroll
        for (int kt = 0; kt < 3; ++kt)
            #pragma unroll
            for (int ky = 0; ky < 3; ++ky)
                #pragma unroll
                for (int kx = 0; kx < 3; ++kx)
                    tap[kt*9 + ky*3 + kx] =
                        pl[(j-1+kt)*(10*LSK) + (lyk+ky)*LSK + (lxk+kx)];
        #pragma unroll
        for (int c = 0; c < 16; ++c) {
            const float* w = wg + (c0 + c)*27;
            float v = 0.f;
            #pragma unroll
            for (int i = 0; i < 27; ++i) v = fmaf(w[i], tap[i], v);
            s[c] += v; q[c] += v*v;
            gout[gbase + ((long)((b*HCN + c)*TT + t))*THW + hw] = f2bf(v);
        }
    }

    // block reduce 16 channels x (sum, sumsq)
    int lane = tid & 63, wid = tid >> 6;
    #pragma unroll
    for (int c = 0; c < 16; ++c) {
        float ss = s[c], qq = q[c];
        #pragma unroll
        for (int off = 32; off > 0; off >>= 1) {
            ss += __shfl_down(ss, off, 64);
            qq += __shfl_down(qq, off, 64);
        }
        if (lane == 0) { redS[wid][c] = ss; redQ[wid][c] = qq; }
    }
    __syncthreads();
    if (tid < 16) {
        int ch = c0 + tid;
        float ss = redS[0][tid] + redS[1][tid] + redS[2][tid] + redS[3][tid];
        float qq = redQ[0][tid] + redQ[1][tid] + redQ[2][tid] + redQ[3][tid];
        atomicAdd(&stats[ch], ss);
        atomicAdd(&stats[32 + ch], qq);
    }
}

// ---------- kernel 3: pointwise BN + act + scan (bf16 in, bf16 h in-place).
// BN params derived inline from raw stats (k2 fused away).
// grid: (25, 16 ch, 2 b), block 256; each thread: 4 consecutive hw elems, scans t
__global__ __launch_bounds__(256)
void k3_scan(unsigned short* __restrict__ g, const float* __restrict__ stats,
             const float* __restrict__ gamma, const float* __restrict__ beta,
             const int* __restrict__ rev_p) {
    int c = blockIdx.y, b = blockIdx.z;
    int p4 = blockIdx.x * blockDim.x + threadIdx.x;    // ushort4 index in plane
    float n = (float)NPER;
    float mz = stats[c] / n,        vz = stats[32 + c] / n - mz*mz;
    float az = gamma[c] * rsqrtf(vz + 1e-5f);
    float bz = beta[c] - mz * az;
    float mf = stats[16 + c] / n,   vf = stats[48 + c] / n - mf*mf;
    float af = gamma[16 + c] * rsqrtf(vf + 1e-5f);
    float bf = beta[16 + c] - mf * af;
    int rev = rev_p[0];

    ushort4* g4 = (ushort4*)g;
    long zb = ((long)((b*HCN + c)*TT)) * (THW/4) + p4;
    long fb = zb + GF_OFF_US/4;

    float h0 = 0.f, h1 = 0.f, h2 = 0.f, h3 = 0.f;

#define K3_STEP(t)                                                        \
    {                                                                     \
        long o = (long)(t) * (THW/4);                                     \
        ushort4 zu = g4[zb + o];                                          \
        ushort4 fu = g4[fb + o];                                          \
        float z0 = tanhf_(fmaf(az, b2f(zu.x), bz));                       \
        float z1 = tanhf_(fmaf(az, b2f(zu.y), bz));                       \
        float z2 = tanhf_(fmaf(az, b2f(zu.z), bz));                       \
        float z3 = tanhf_(fmaf(az, b2f(zu.w), bz));                       \
        float f0 = sigmoidf_(fmaf(af, b2f(fu.x), bf));                    \
        float f1 = sigmoidf_(fmaf(af, b2f(fu.y), bf));                    \
        float f2 = sigmoidf_(fmaf(af, b2f(fu.z), bf));                    \
        float f3 = sigmoidf_(fmaf(af, b2f(fu.w), bf));                    \
        h0 = f0*h0 + (1.f - f0)*z0;                                       \
        h1 = f1*h1 + (1.f - f1)*z1;                                       \
        h2 = f2*h2 + (1.f - f2)*z2;                                       \
        h3 = f3*h3 + (1.f - f3)*z3;                                       \
        ushort4 hu;                                                       \
        hu.x = f2bf(h0); hu.y = f2bf(h1); hu.z = f2bf(h2); hu.w = f2bf(h3); \
        g4[zb + o] = hu;                                                  \
    }

    if (!rev) {
        for (int t = 0; t < TT; ++t) K3_STEP(t)
    } else {
        for (int t = TT - 1; t >= 0; --t) K3_STEP(t)
    }
#undef K3_STEP
}

// ---------- kernel 4: conv2+conv3 over bf16 h — NO LDS, NO BARRIERS (R12-proven).
// Each thread: 2 x-outputs; per plane, 3 aligned uint (bf16-pair) loads per row
// straight from global. Edge zero-padding folded into precomputed AND-masks.
// c2/c3 stored as bf16 (ushort2) — halves k4 write + k6 read traffic.
// grid: (50 tiles 32x16, 8 t-chunks of 4, 2 b), block 256
#define K4TCH 4
__global__ __launch_bounds__(256)
void k4_conv23(const unsigned short* __restrict__ hb, const float* __restrict__ wsc,
               const float* __restrict__ wsh, unsigned short* __restrict__ c2,
               unsigned short* __restrict__ c3, float* __restrict__ stats2) {
    __shared__ float red[4][4];

    int b  = blockIdx.z;
    int t0 = blockIdx.y * K4TCH;
    int t1 = min(t0 + K4TCH - 1, TT - 1);
    int tile = blockIdx.x;
    int ty0 = (tile / 5) * 16, tx0 = (tile % 5) * 32;
    int tid = threadIdx.x;
    int k   = tid & 15;            // x-pair index
    int ly  = tid >> 4;            // row 0..15
    int y = ty0 + ly, x0 = tx0 + 2*k;

    int ts = max(t0 - 1, 0), te = min(t1 + 1, TT - 1);
    int nplanes = (te - ts + 1) * 8;

    // per-thread constants: uint element offsets within a plane, per-row masks
    int e0 = max(x0 - 2, 0) >> 1;
    int e1 = x0 >> 1;
    int e2 = min(x0 + 2, TW - 2) >> 1;
    unsigned int mL = (x0 == 0)      ? 0u : 0xffff0000u;
    unsigned int mR = (x0 == TW - 2) ? 0u : 0x0000ffffu;
    int rowb[3];
    unsigned int mHi0[3], mRow[3], mLo2[3];
    #pragma unroll
    for (int ky = 0; ky < 3; ++ky) {
        int gy = y - 1 + ky;
        bool ok = (gy >= 0 && gy < TH);
        int gyc = min(max(gy, 0), TH - 1);
        rowb[ky] = gyc * (TW/2);
        unsigned int rm = ok ? 0xffffffffu : 0u;
        mHi0[ky] = rm & mL;
        mRow[ky] = rm;
        mLo2[ky] = rm & mR;
    }

    float aP2x=0.f,aP2y=0.f,aC2x=0.f,aC2y=0.f,aN2x=0.f,aN2y=0.f;
    float aP3x=0.f,aP3y=0.f,aC3x=0.f,aC3y=0.f,aN3x=0.f,aN3y=0.f;
    float s2l = 0.f, q2l = 0.f, s3l = 0.f, q3l = 0.f;

    #pragma unroll 1
    for (int p = 0; p < nplanes; ++p) {
        int c = p & 7, t_in = ts + (p >> 3);
        const unsigned int* p2 = (const unsigned int*)(hb + ((long)((b*HCN + c)*TT + t_in))*THW);
        const unsigned int* p3 = (const unsigned int*)(hb + ((long)((b*HCN + 8 + c)*TT + t_in))*THW);
        const float* w2 = wsc + c*27;
        const float* w3 = wsh + c*27;

        #pragma unroll
        for (int ky = 0; ky < 3; ++ky) {
            int rb = rowb[ky];
            // conv2
            {
                unsigned int u0 = p2[rb + e0];
                unsigned int u1 = p2[rb + e1];
                unsigned int u2 = p2[rb + e2];
                float v1 = __uint_as_float(u0 & mHi0[ky]);         // x0-1
                unsigned int tm = u1 & mRow[ky];
                float v2 = __uint_as_float(tm << 16);              // x0
                float v3 = __uint_as_float(tm & 0xffff0000u);      // x0+1
                float v4 = __uint_as_float((u2 & mLo2[ky]) << 16); // x0+2
                float wN0 = w2[ky*3+0],   wN1 = w2[ky*3+1],   wN2 = w2[ky*3+2];
                float wC0 = w2[9+ky*3+0], wC1 = w2[9+ky*3+1], wC2 = w2[9+ky*3+2];
                float wP0 = w2[18+ky*3+0],wP1 = w2[18+ky*3+1],wP2 = w2[18+ky*3+2];
                aN2x = fmaf(wN0,v1,aN2x); aN2x = fmaf(wN1,v2,aN2x); aN2x = fmaf(wN2,v3,aN2x);
                aN2y = fmaf(wN0,v2,aN2y); aN2y = fmaf(wN1,v3,aN2y); aN2y = fmaf(wN2,v4,aN2y);
                aC2x = fmaf(wC0,v1,aC2x); aC2x = fmaf(wC1,v2,aC2x); aC2x = fmaf(wC2,v3,aC2x);
                aC2y = fmaf(wC0,v2,aC2y); aC2y = fmaf(wC1,v3,aC2y); aC2y = fmaf(wC2,v4,aC2y);
                aP2x = fmaf(wP0,v1,aP2x); aP2x = fmaf(wP1,v2,aP2x); aP2x = fmaf(wP2,v3,aP2x);
                aP2y = fmaf(wP0,v2,aP2y); aP2y = fmaf(wP1,v3,aP2y); aP2y = fmaf(wP2,v4,aP2y);
            }
            // conv3
            {
                unsigned int u0 = p3[rb + e0];
                unsigned int u1 = p3[rb + e1];
                unsigned int u2 = p3[rb + e2];
                float v1 = __uint_as_float(u0 & mHi0[ky]);
                unsigned int tm = u1 & mRow[ky];
                float v2 = __uint_as_float(tm << 16);
                float v3 = __uint_as_float(tm & 0xffff0000u);
                float v4 = __uint_as_float((u2 & mLo2[ky]) << 16);
                float wN0 = w3[ky*3+0],   wN1 = w3[ky*3+1],   wN2 = w3[ky*3+2];
                float wC0 = w3[9+ky*3+0], wC1 = w3[9+ky*3+1], wC2 = w3[9+ky*3+2];
                float wP0 = w3[18+ky*3+0],wP1 = w3[18+ky*3+1],wP2 = w3[18+ky*3+2];
                aN3x = fmaf(wN0,v1,aN3x); aN3x = fmaf(wN1,v2,aN3x); aN3x = fmaf(wN2,v3,aN3x);
                aN3y = fmaf(wN0,v2,aN3y); aN3y = fmaf(wN1,v3,aN3y); aN3y = fmaf(wN2,v4,aN3y);
                aC3x = fmaf(wC0,v1,aC3x); aC3x = fmaf(wC1,v2,aC3x); aC3x = fmaf(wC2,v3,aC3x);
                aC3y = fmaf(wC0,v2,aC3y); aC3y = fmaf(wC1,v3,aC3y); aC3y = fmaf(wC2,v4,aC3y);
                aP3x = fmaf(wP0,v1,aP3x); aP3x = fmaf(wP1,v2,aP3x); aP3x = fmaf(wP2,v3,aP3x);
                aP3y = fmaf(wP0,v2,aP3y); aP3y = fmaf(wP1,v3,aP3y); aP3y = fmaf(wP2,v4,aP3y);
            }
        }

        if (c == 7) {
            int t_out = t_in - 1;
            if (t_out >= t0 && t_out <= t1) {
                long oidx = ((long)(b*TT + t_out)) * THW + (long)y*TW + x0;
                ushort2 o2; o2.x = f2bf(aP2x); o2.y = f2bf(aP2y);
                ushort2 o3; o3.x = f2bf(aP3x); o3.y = f2bf(aP3y);
                *(ushort2*)&c2[oidx] = o2;
                *(ushort2*)&c3[oidx] = o3;
                s2l += aP2x + aP2y; q2l += aP2x*aP2x + aP2y*aP2y;
                s3l += aP3x + aP3y; q3l += aP3x*aP3x + aP3y*aP3y;
            }
            aP2x=aC2x; aC2x=aN2x; aN2x=0.f;  aP2y=aC2y; aC2y=aN2y; aN2y=0.f;
            aP3x=aC3x; aC3x=aN3x; aN3x=0.f;  aP3y=aC3y; aC3y=aN3y; aN3y=0.f;
        }
    }
    if (t1 == TT - 1) {
        long oidx = ((long)(b*TT + (TT - 1))) * THW + (long)y*TW + x0;
        ushort2 o2; o2.x = f2bf(aP2x); o2.y = f2bf(aP2y);
        ushort2 o3; o3.x = f2bf(aP3x); o3.y = f2bf(aP3y);
        *(ushort2*)&c2[oidx] = o2;
        *(ushort2*)&c3[oidx] = o3;
        s2l += aP2x + aP2y; q2l += aP2x*aP2x + aP2y*aP2y;
        s3l += aP3x + aP3y; q3l += aP3x*aP3x + aP3y*aP3y;
    }

    #pragma unroll
    for (int off = 32; off > 0; off >>= 1) {
        s2l += __shfl_down(s2l, off, 64);
        q2l += __shfl_down(q2l, off, 64);
        s3l += __shfl_down(s3l, off, 64);
        q3l += __shfl_down(q3l, off, 64);
    }
    int lane = tid & 63, wid = tid >> 6;
    if (lane == 0) { red[0][wid] = s2l; red[1][wid] = q2l; red[2][wid] = s3l; red[3][wid] = q3l; }
    __syncthreads();
    if (tid == 0) {
        #pragma unroll
        for (int j = 0; j < 4; ++j)
            atomicAdd(&stats2[j], red[j][0] + red[j][1] + red[j][2] + red[j][3]);
    }
}

// ---------- kernel 6: epilogue (k5 fused in: BN params derived inline) ----------
// reads bf16 c2/c3 (ushort4 = 4 elems), writes float4 x2
__global__ __launch_bounds__(256)
void k6_final(const ushort4* __restrict__ c2, const ushort4* __restrict__ c3,
              const float* __restrict__ stats2,
              const float* __restrict__ gs, const float* __restrict__ bs,
              const float* __restrict__ gt, const float* __restrict__ bt,
              float4* __restrict__ out) {
    int i = blockIdx.x * blockDim.x + threadIdx.x;
    if (i < NPER/4) {
        float n = (float)NPER;
        float m2 = stats2[0] / n, v2v = stats2[1] / n - m2*m2;
        float a2 = gs[0] * rsqrtf(v2v + 1e-5f);
        float b2 = bs[0] - m2*a2;
        float m3 = stats2[2] / n, v3v = stats2[3] / n - m3*m3;
        float a3 = gt[0] * rsqrtf(v3v + 1e-5f);
        float b3 = bt[0] - m3*a3;

        ushort4 u2 = c2[i], u3 = c3[i];
        float4 sc, sh;
        sc.x = sigmoidf_(fmaf(a2, b2f(u2.x), b2) + 2.f) + 1e-4f;
        sc.y = sigmoidf_(fmaf(a2, b2f(u2.y), b2) + 2.f) + 1e-4f;
        sc.z = sigmoidf_(fmaf(a2, b2f(u2.z), b2) + 2.f) + 1e-4f;
        sc.w = sigmoidf_(fmaf(a2, b2f(u2.w), b2) + 2.f) + 1e-4f;
        sh.x = fmaf(a3, b2f(u3.x), b3);
        sh.y = fmaf(a3, b2f(u3.y), b3);
        sh.z = fmaf(a3, b2f(u3.z), b3);
        sh.w = fmaf(a3, b2f(u3.w), b3);
        out[i] = sc;
        out[NPER/4 + i] = sh;
    }
}

// ---------- launch ----------
extern "C" void kernel_launch(void* const* d_in, const int* in_sizes, int n_in,
                              void* d_out, int out_size, void* d_ws, size_t ws_size,
                              hipStream_t stream) {
    const float* in          = (const float*)d_in[0];
    const float* w_gate      = (const float*)d_in[1];
    const float* gamma_gate  = (const float*)d_in[2];
    const float* beta_gate   = (const float*)d_in[3];
    const float* w_scale     = (const float*)d_in[4];
    const float* gamma_scale = (const float*)d_in[5];
    const float* beta_scale  = (const float*)d_in[6];
    const float* w_shift     = (const float*)d_in[7];
    const float* gamma_shift = (const float*)d_in[8];
    const float* beta_shift  = (const float*)d_in[9];
    const int*   rev         = (const int*)d_in[10];

    unsigned short* g   = (unsigned short*)d_ws;                    // gates bf16 (z then f); z-half becomes h
    unsigned short* c2b = (unsigned short*)((char*)d_ws + C2_BYTE); // bf16, aliases dead f-gates
    unsigned short* c3b = c2b + NPER;
    float* st  = (float*)((char*)d_ws + STATS_BYTE);
    float* s1  = st;            // 64: sum[32], sumsq[32]
    float* s2  = st + 64;       // 4: sum2,sumsq2,sum3,sumsq3
    float* out = (float*)d_out;

    hipMemsetAsync(st, 0, 68 * sizeof(float), stream);

    k1_gates_stats<<<dim3(8, 100, TB), 256, 0, stream>>>(in, w_gate, g, s1);
    k3_scan<<<dim3(25, HCN, TB), 256, 0, stream>>>(g, s1, gamma_gate, beta_gate, rev);
    k4_conv23<<<dim3(50, 8, TB), 256, 0, stream>>>(g, w_scale, w_shift, c2b, c3b, s2);
    k6_final<<<(NPER/4 + 255)/256, 256, 0, stream>>>((const ushort4*)c2b, (const ushort4*)c3b,
                                                     s2, gamma_scale, beta_scale,
                                                     gamma_shift, beta_shift, (float4*)out);
}